// Round 1
// baseline (63.605 us; speedup 1.0000x reference)
//
#include <hip/hip_runtime.h>
#include <math.h>

#define BATCH 64
#define LSEQ 4096
#define CH 128
#define NCHUNK 16
#define CHROWS (LSEQ / NCHUNK)   // 256
#define TYDIM 8
#define TROWS (CHROWS / TYDIM)   // 32
#define RECENT_START 3072
#define NRECENT (LSEQ - RECENT_START)  // 1024

// ---------------- Kernel 1: per-chunk partial sums ----------------
// grid (NCHUNK, BATCH), block 256 = (c4: 32) x (ty: 8)
// Each thread: 4 channels (float4), TROWS consecutive rows.
// Partials per (b, chunk, c): 0:sx 1:sx2 2:sx3 3:sd 4:sd2 5:sr 6:sr2
__global__ __launch_bounds__(256) void k_stats_partial(
    const float* __restrict__ x, float* __restrict__ ws) {
  const int tid = threadIdx.x;
  const int c4 = tid & 31;        // float4 group -> channels 4*c4..4*c4+3
  const int ty = tid >> 5;        // 0..7
  const int chk = blockIdx.x;
  const int b = blockIdx.y;
  const int ts = chk * CHROWS + ty * TROWS;   // first row for this thread

  const float4* px =
      reinterpret_cast<const float4*>(x + ((size_t)b * LSEQ + ts) * CH) + c4;
  const int rowstep = CH / 4;  // 32 float4 per row

  float sx[4] = {0, 0, 0, 0}, sx2[4] = {0, 0, 0, 0}, sx3[4] = {0, 0, 0, 0};
  float sd[4] = {0, 0, 0, 0}, sd2[4] = {0, 0, 0, 0};

  float4 v0 = px[0];
  float pv[4] = {v0.x, v0.y, v0.z, v0.w};
#pragma unroll
  for (int k = 0; k < 4; k++) {
    float f = pv[k];
    sx[k] += f; sx2[k] += f * f; sx3[k] += f * f * f;
  }
#pragma unroll 4
  for (int i = 1; i < TROWS; i++) {
    float4 u = px[i * rowstep];
    float cur[4] = {u.x, u.y, u.z, u.w};
#pragma unroll
    for (int k = 0; k < 4; k++) {
      float f = cur[k];
      sx[k] += f; sx2[k] += f * f; sx3[k] += f * f * f;
      float d = f - pv[k];
      sd[k] += d; sd2[k] += d * d;
      pv[k] = f;
    }
  }
  // boundary diff: between last row of this thread and first row of next range
  if (ts + TROWS < LSEQ) {
    float4 u = px[TROWS * rowstep];
    float cur[4] = {u.x, u.y, u.z, u.w};
#pragma unroll
    for (int k = 0; k < 4; k++) {
      float d = cur[k] - pv[k];
      sd[k] += d; sd2[k] += d * d;
    }
  }

  const bool rec = (ts >= RECENT_START);  // uniform over the thread's 32 rows

  float acc[7][4];
#pragma unroll
  for (int k = 0; k < 4; k++) {
    acc[0][k] = sx[k];
    acc[1][k] = sx2[k];
    acc[2][k] = sx3[k];
    acc[3][k] = sd[k];
    acc[4][k] = sd2[k];
    acc[5][k] = rec ? sx[k] : 0.f;
    acc[6][k] = rec ? sx2[k] : 0.f;
  }

  __shared__ float4 buf[256];
  float* wsb = ws + ((size_t)(b * NCHUNK + chk) * 7) * CH;
#pragma unroll 1
  for (int s = 0; s < 7; s++) {
    buf[tid] = make_float4(acc[s][0], acc[s][1], acc[s][2], acc[s][3]);
    __syncthreads();
    if (tid < 32) {
      float4 r = buf[tid];
#pragma unroll
      for (int k = 1; k < 8; k++) {
        float4 o = buf[tid + 32 * k];
        r.x += o.x; r.y += o.y; r.z += o.z; r.w += o.w;
      }
      reinterpret_cast<float4*>(wsb + s * CH)[tid] = r;
    }
    __syncthreads();
  }
}

// ---------------- Kernel 2: finalize stats + MLP ----------------
// grid (BATCH), block 128
__global__ __launch_bounds__(128) void k_stats_mlp(
    const float* __restrict__ ws,
    const float* __restrict__ W1, const float* __restrict__ b1,
    const float* __restrict__ W2, const float* __restrict__ b2,
    const float* __restrict__ W3, const float* __restrict__ b3,
    float* __restrict__ out) {
  const int b = blockIdx.x;
  const int tx = threadIdx.x;  // channel / feature index

  __shared__ float stats[6 * CH];
  __shared__ float h1[128];
  __shared__ float h2[32];

  float t[7] = {0, 0, 0, 0, 0, 0, 0};
#pragma unroll 1
  for (int chk = 0; chk < NCHUNK; chk++) {
    const float* p = ws + ((size_t)(b * NCHUNK + chk) * 7) * CH + tx;
#pragma unroll
    for (int s = 0; s < 7; s++) t[s] += p[s * CH];
  }

  const float Lf = (float)LSEQ;
  float mean = t[0] / Lf;
  float var = fmaxf(t[1] - Lf * mean * mean, 0.f) / (Lf - 1.f);
  float stdE = sqrtf(var) + 1e-8f;
  float m3 = t[2] / Lf - 3.f * mean * (t[1] / Lf) + 2.f * mean * mean * mean;
  float skew = m3 / (stdE * stdE * stdE);
  const float nd = (float)(LSEQ - 1);
  float dmean = t[3] / nd;
  float dvar = fmaxf(t[4] - nd * dmean * dmean, 0.f) / (nd - 1.f);
  float dstd = sqrtf(dvar);
  const float nr = (float)NRECENT;
  float rmean = t[5] / nr;
  float rvar = fmaxf(t[6] - nr * rmean * rmean, 0.f) / (nr - 1.f);
  float rstd = sqrtf(rvar) + 1e-8f;

  stats[0 * CH + tx] = mean;
  stats[1 * CH + tx] = stdE;
  stats[2 * CH + tx] = skew;
  stats[3 * CH + tx] = dstd;
  stats[4 * CH + tx] = rmean;
  stats[5 * CH + tx] = rstd;
  __syncthreads();

  // layer 1: (768) @ (768,128)
  float a1 = b1[tx];
#pragma unroll 8
  for (int k = 0; k < 6 * CH; k++) a1 = fmaf(stats[k], W1[k * 128 + tx], a1);
  h1[tx] = 0.5f * a1 * (1.f + erff(a1 * 0.70710678118654752f));
  __syncthreads();

  // layer 2: (128) @ (128,32)
  if (tx < 32) {
    float a2 = b2[tx];
#pragma unroll 8
    for (int k = 0; k < 128; k++) a2 = fmaf(h1[k], W2[k * 32 + tx], a2);
    h2[tx] = 0.5f * a2 * (1.f + erff(a2 * 0.70710678118654752f));
  }
  __syncthreads();

  // layer 3: (32) @ (32,128) + sigmoid
  float a3 = b3[tx];
#pragma unroll
  for (int j = 0; j < 32; j++) a3 = fmaf(h2[j], W3[j * 128 + tx], a3);
  out[(size_t)b * CH + tx] = 1.f / (1.f + expf(-a3));
}

extern "C" void kernel_launch(void* const* d_in, const int* in_sizes, int n_in,
                              void* d_out, int out_size, void* d_ws,
                              size_t ws_size, hipStream_t stream) {
  const float* x = (const float*)d_in[0];
  const float* W1 = (const float*)d_in[1];
  const float* b1 = (const float*)d_in[2];
  const float* W2 = (const float*)d_in[3];
  const float* b2 = (const float*)d_in[4];
  const float* W3 = (const float*)d_in[5];
  const float* b3 = (const float*)d_in[6];
  float* out = (float*)d_out;
  float* ws = (float*)d_ws;

  dim3 g1(NCHUNK, BATCH);
  k_stats_partial<<<g1, 256, 0, stream>>>(x, ws);
  k_stats_mlp<<<BATCH, 128, 0, stream>>>(ws, W1, b1, W2, b2, W3, b3, out);
}

// Round 2
// 55.272 us; speedup vs baseline: 1.1508x; 1.1508x over previous
//
#include <hip/hip_runtime.h>
#include <math.h>

#define BATCH 64
#define LSEQ 4096
#define CH 128
#define NCHUNK 32
#define CHROWS (LSEQ / NCHUNK)   // 128
#define TYDIM 8
#define TROWS (CHROWS / TYDIM)   // 16
#define RECENT_CHUNK 24          // chunks >= 24 are the recent window (3072..4095)
#define NRECENT 1024

// ---------------- Kernel 1: per-chunk partial sums ----------------
// grid (NCHUNK, BATCH), block 256 = (c4: 32) x (ty: 8)
// Each thread: 4 channels (float4), TROWS consecutive rows.
// ws layout per (b,chunk): 5 slots x 128 ch: 0:sx 1:sx2 2:sx3 3:sd 4:sd2
__global__ __launch_bounds__(256) void k_stats_partial(
    const float* __restrict__ x, float* __restrict__ ws) {
  const int tid = threadIdx.x;
  const int c4 = tid & 31;        // float4 group -> channels 4*c4..4*c4+3
  const int ty = tid >> 5;        // 0..7
  const int chk = blockIdx.x;
  const int b = blockIdx.y;
  const int ts = chk * CHROWS + ty * TROWS;   // first row for this thread

  const float4* px =
      reinterpret_cast<const float4*>(x + ((size_t)b * LSEQ + ts) * CH) + c4;
  const int rowstep = CH / 4;  // 32 float4 per row

  float sx[4] = {0, 0, 0, 0}, sx2[4] = {0, 0, 0, 0}, sx3[4] = {0, 0, 0, 0};
  float sd2[4] = {0, 0, 0, 0};
  float pv[4], first[4], sd[4];

  float4 v0 = px[0];
  pv[0] = first[0] = v0.x;
  pv[1] = first[1] = v0.y;
  pv[2] = first[2] = v0.z;
  pv[3] = first[3] = v0.w;
#pragma unroll
  for (int k = 0; k < 4; k++) {
    float f = pv[k], ff = f * f;
    sx[k] += f; sx2[k] += ff; sx3[k] = fmaf(ff, f, sx3[k]);
  }
#pragma unroll 5
  for (int i = 1; i < TROWS; i++) {
    float4 u = px[i * rowstep];
    float cur[4] = {u.x, u.y, u.z, u.w};
#pragma unroll
    for (int k = 0; k < 4; k++) {
      float f = cur[k], ff = f * f;
      sx[k] += f; sx2[k] += ff; sx3[k] = fmaf(ff, f, sx3[k]);
      float d = f - pv[k];
      sd2[k] = fmaf(d, d, sd2[k]);
      pv[k] = f;
    }
  }
  // boundary diff with first row of the next thread's range (telescoped sd)
  if (ts + TROWS < LSEQ) {
    float4 u = px[TROWS * rowstep];
    float cur[4] = {u.x, u.y, u.z, u.w};
#pragma unroll
    for (int k = 0; k < 4; k++) {
      float d = cur[k] - pv[k];
      sd2[k] = fmaf(d, d, sd2[k]);
      sd[k] = cur[k] - first[k];   // sum of the TROWS diffs this thread owns
    }
  } else {
#pragma unroll
    for (int k = 0; k < 4; k++) sd[k] = pv[k] - first[k];  // last thread: TROWS-1 diffs
  }

  // in-wave fold across the ty pair sharing this wave (lane ^ 32)
  float vals[20];
#pragma unroll
  for (int k = 0; k < 4; k++) {
    vals[0 + k] = sx[k];
    vals[4 + k] = sx2[k];
    vals[8 + k] = sx3[k];
    vals[12 + k] = sd[k];
    vals[16 + k] = sd2[k];
  }
#pragma unroll
  for (int j = 0; j < 20; j++) vals[j] += __shfl_xor(vals[j], 32);

  __shared__ float4 red[5][4][32];  // [stat][wave][c4]
  const int w = tid >> 6;
  const int lane = tid & 63;
  if (lane < 32) {
#pragma unroll
    for (int s = 0; s < 5; s++)
      red[s][w][c4] = make_float4(vals[s * 4 + 0], vals[s * 4 + 1],
                                  vals[s * 4 + 2], vals[s * 4 + 3]);
  }
  __syncthreads();
  if (tid < 160) {
    const int s = tid >> 5, c = tid & 31;
    float4 r = red[s][0][c];
    float4 r1 = red[s][1][c], r2 = red[s][2][c], r3 = red[s][3][c];
    r.x += r1.x + r2.x + r3.x;
    r.y += r1.y + r2.y + r3.y;
    r.z += r1.z + r2.z + r3.z;
    r.w += r1.w + r2.w + r3.w;
    float* wsb = ws + ((size_t)(b * NCHUNK + chk) * 5 + s) * CH;
    reinterpret_cast<float4*>(wsb)[c] = r;
  }
}

// ---------------- Kernel 2: finalize stats + MLP ----------------
// grid (BATCH), block 128
__global__ __launch_bounds__(128) void k_stats_mlp(
    const float* __restrict__ ws,
    const float* __restrict__ W1, const float* __restrict__ b1,
    const float* __restrict__ W2, const float* __restrict__ b2,
    const float* __restrict__ W3, const float* __restrict__ b3,
    float* __restrict__ out) {
  const int b = blockIdx.x;
  const int tx = threadIdx.x;  // channel / feature index

  __shared__ float stats[6 * CH];
  __shared__ float h1[128];
  __shared__ float h2[32];

  float t0 = 0, t1 = 0, t2 = 0, t3 = 0, t4 = 0, t5 = 0, t6 = 0;
#pragma unroll 1
  for (int chk = 0; chk < NCHUNK; chk++) {
    const float* p = ws + ((size_t)(b * NCHUNK + chk) * 5) * CH + tx;
    float a = p[0 * CH], s2 = p[1 * CH], s3 = p[2 * CH];
    float d1 = p[3 * CH], d2v = p[4 * CH];
    t0 += a; t1 += s2; t2 += s3; t3 += d1; t4 += d2v;
    if (chk >= RECENT_CHUNK) { t5 += a; t6 += s2; }  // uniform branch
  }

  const float Lf = (float)LSEQ;
  float mean = t0 / Lf;
  float var = fmaxf(t1 - Lf * mean * mean, 0.f) / (Lf - 1.f);
  float stdE = sqrtf(var) + 1e-8f;
  float m3 = t2 / Lf - 3.f * mean * (t1 / Lf) + 2.f * mean * mean * mean;
  float skew = m3 / (stdE * stdE * stdE);
  const float nd = (float)(LSEQ - 1);
  float dmean = t3 / nd;
  float dvar = fmaxf(t4 - nd * dmean * dmean, 0.f) / (nd - 1.f);
  float dstd = sqrtf(dvar);
  const float nr = (float)NRECENT;
  float rmean = t5 / nr;
  float rvar = fmaxf(t6 - nr * rmean * rmean, 0.f) / (nr - 1.f);
  float rstd = sqrtf(rvar) + 1e-8f;

  stats[0 * CH + tx] = mean;
  stats[1 * CH + tx] = stdE;
  stats[2 * CH + tx] = skew;
  stats[3 * CH + tx] = dstd;
  stats[4 * CH + tx] = rmean;
  stats[5 * CH + tx] = rstd;
  __syncthreads();

  // layer 1: (768) @ (768,128), 4-way ILP on the dependent chain
  {
    float a0 = 0, a1 = 0, a2 = 0, a3 = 0;
#pragma unroll 4
    for (int k = 0; k < 6 * CH; k += 4) {
      a0 = fmaf(stats[k + 0], W1[(k + 0) * 128 + tx], a0);
      a1 = fmaf(stats[k + 1], W1[(k + 1) * 128 + tx], a1);
      a2 = fmaf(stats[k + 2], W1[(k + 2) * 128 + tx], a2);
      a3 = fmaf(stats[k + 3], W1[(k + 3) * 128 + tx], a3);
    }
    float a = ((a0 + a1) + (a2 + a3)) + b1[tx];
    h1[tx] = 0.5f * a * (1.f + erff(a * 0.70710678118654752f));
  }
  __syncthreads();

  // layer 2: (128) @ (128,32)
  if (tx < 32) {
    float a0 = 0, a1 = 0, a2 = 0, a3 = 0;
#pragma unroll 4
    for (int k = 0; k < 128; k += 4) {
      a0 = fmaf(h1[k + 0], W2[(k + 0) * 32 + tx], a0);
      a1 = fmaf(h1[k + 1], W2[(k + 1) * 32 + tx], a1);
      a2 = fmaf(h1[k + 2], W2[(k + 2) * 32 + tx], a2);
      a3 = fmaf(h1[k + 3], W2[(k + 3) * 32 + tx], a3);
    }
    float a = ((a0 + a1) + (a2 + a3)) + b2[tx];
    h2[tx] = 0.5f * a * (1.f + erff(a * 0.70710678118654752f));
  }
  __syncthreads();

  // layer 3: (32) @ (32,128) + sigmoid
  {
    float a0 = 0, a1 = 0, a2 = 0, a3 = 0;
#pragma unroll
    for (int j = 0; j < 32; j += 4) {
      a0 = fmaf(h2[j + 0], W3[(j + 0) * 128 + tx], a0);
      a1 = fmaf(h2[j + 1], W3[(j + 1) * 128 + tx], a1);
      a2 = fmaf(h2[j + 2], W3[(j + 2) * 128 + tx], a2);
      a3 = fmaf(h2[j + 3], W3[(j + 3) * 128 + tx], a3);
    }
    float a = ((a0 + a1) + (a2 + a3)) + b3[tx];
    out[(size_t)b * CH + tx] = 1.f / (1.f + expf(-a));
  }
}

extern "C" void kernel_launch(void* const* d_in, const int* in_sizes, int n_in,
                              void* d_out, int out_size, void* d_ws,
                              size_t ws_size, hipStream_t stream) {
  const float* x = (const float*)d_in[0];
  const float* W1 = (const float*)d_in[1];
  const float* b1 = (const float*)d_in[2];
  const float* W2 = (const float*)d_in[3];
  const float* b2 = (const float*)d_in[4];
  const float* W3 = (const float*)d_in[5];
  const float* b3 = (const float*)d_in[6];
  float* out = (float*)d_out;
  float* ws = (float*)d_ws;

  dim3 g1(NCHUNK, BATCH);
  k_stats_partial<<<g1, 256, 0, stream>>>(x, ws);
  k_stats_mlp<<<BATCH, 128, 0, stream>>>(ws, W1, b1, W2, b2, W3, b3, out);
}

// Round 3
// 37.145 us; speedup vs baseline: 1.7124x; 1.4880x over previous
//
#include <hip/hip_runtime.h>
#include <math.h>

#define BATCH 64
#define LSEQ 4096
#define CH 128
#define NCHUNK 32
#define CHROWS (LSEQ / NCHUNK)   // 128
#define TYDIM 8
#define TROWS (CHROWS / TYDIM)   // 16
#define RECENT_CHUNK 24          // chunks >= 24 are the recent window (3072..4095)
#define NRECENT 1024

// ---------------- Kernel 1: per-chunk partial sums ----------------
// grid (NCHUNK, BATCH), block 256 = (c4: 32) x (ty: 8)
// ws layout per (b,chunk): 5 slots x 128 ch: 0:sx 1:sx2 2:sx3 3:sd 4:sd2
__global__ __launch_bounds__(256) void k_stats_partial(
    const float* __restrict__ x, float* __restrict__ ws) {
  const int tid = threadIdx.x;
  const int c4 = tid & 31;        // float4 group -> channels 4*c4..4*c4+3
  const int ty = tid >> 5;        // 0..7
  const int chk = blockIdx.x;
  const int b = blockIdx.y;
  const int ts = chk * CHROWS + ty * TROWS;   // first row for this thread

  const float4* px =
      reinterpret_cast<const float4*>(x + ((size_t)b * LSEQ + ts) * CH) + c4;
  const int rowstep = CH / 4;  // 32 float4 per row

  float sx[4] = {0, 0, 0, 0}, sx2[4] = {0, 0, 0, 0}, sx3[4] = {0, 0, 0, 0};
  float sd2[4] = {0, 0, 0, 0};
  float pv[4], first[4], sd[4];

  float4 v0 = px[0];
  pv[0] = first[0] = v0.x;
  pv[1] = first[1] = v0.y;
  pv[2] = first[2] = v0.z;
  pv[3] = first[3] = v0.w;
#pragma unroll
  for (int k = 0; k < 4; k++) {
    float f = pv[k], ff = f * f;
    sx[k] += f; sx2[k] += ff; sx3[k] = fmaf(ff, f, sx3[k]);
  }
#pragma unroll 5
  for (int i = 1; i < TROWS; i++) {
    float4 u = px[i * rowstep];
    float cur[4] = {u.x, u.y, u.z, u.w};
#pragma unroll
    for (int k = 0; k < 4; k++) {
      float f = cur[k], ff = f * f;
      sx[k] += f; sx2[k] += ff; sx3[k] = fmaf(ff, f, sx3[k]);
      float d = f - pv[k];
      sd2[k] = fmaf(d, d, sd2[k]);
      pv[k] = f;
    }
  }
  // boundary diff with first row of the next thread's range (telescoped sd)
  if (ts + TROWS < LSEQ) {
    float4 u = px[TROWS * rowstep];
    float cur[4] = {u.x, u.y, u.z, u.w};
#pragma unroll
    for (int k = 0; k < 4; k++) {
      float d = cur[k] - pv[k];
      sd2[k] = fmaf(d, d, sd2[k]);
      sd[k] = cur[k] - first[k];   // sum of the TROWS diffs this thread owns
    }
  } else {
#pragma unroll
    for (int k = 0; k < 4; k++) sd[k] = pv[k] - first[k];  // last thread: TROWS-1 diffs
  }

  // in-wave fold across the ty pair sharing this wave (lane ^ 32)
  float vals[20];
#pragma unroll
  for (int k = 0; k < 4; k++) {
    vals[0 + k] = sx[k];
    vals[4 + k] = sx2[k];
    vals[8 + k] = sx3[k];
    vals[12 + k] = sd[k];
    vals[16 + k] = sd2[k];
  }
#pragma unroll
  for (int j = 0; j < 20; j++) vals[j] += __shfl_xor(vals[j], 32);

  __shared__ float4 red[5][4][32];  // [stat][wave][c4]
  const int w = tid >> 6;
  const int lane = tid & 63;
  if (lane < 32) {
#pragma unroll
    for (int s = 0; s < 5; s++)
      red[s][w][c4] = make_float4(vals[s * 4 + 0], vals[s * 4 + 1],
                                  vals[s * 4 + 2], vals[s * 4 + 3]);
  }
  __syncthreads();
  if (tid < 160) {
    const int s = tid >> 5, c = tid & 31;
    float4 r = red[s][0][c];
    float4 r1 = red[s][1][c], r2 = red[s][2][c], r3 = red[s][3][c];
    r.x += r1.x + r2.x + r3.x;
    r.y += r1.y + r2.y + r3.y;
    r.z += r1.z + r2.z + r3.z;
    r.w += r1.w + r2.w + r3.w;
    float* wsb = ws + ((size_t)(b * NCHUNK + chk) * 5 + s) * CH;
    reinterpret_cast<float4*>(wsb)[c] = r;
  }
}

// ---------------- Kernel 2: finalize stats + MLP (512 thr, split-K) -------
// grid (BATCH), block 512: f = tid&127, q = tid>>7 (0..3)
__global__ __launch_bounds__(512) void k_stats_mlp(
    const float* __restrict__ ws,
    const float* __restrict__ W1, const float* __restrict__ b1,
    const float* __restrict__ W2, const float* __restrict__ b2,
    const float* __restrict__ W3, const float* __restrict__ b3,
    float* __restrict__ out) {
  const int b = blockIdx.x;
  const int tid = threadIdx.x;
  const int f = tid & 127;
  const int q = tid >> 7;  // 0..3

  __shared__ float part[5][4][CH];
  __shared__ float stats[6 * CH];
  __shared__ float h1p[4][128];
  __shared__ float h1[128];
  __shared__ float h2p[16][32];
  __shared__ float h2[32];
  __shared__ float l3p[4][128];

  // ---- chunk reduce: quarter q sums chunks [8q, 8q+8) for channel f ----
  {
    float t0 = 0, t1 = 0, t2 = 0, t3 = 0, t4 = 0;
#pragma unroll
    for (int chk = q * 8; chk < q * 8 + 8; chk++) {
      const float* p = ws + ((size_t)(b * NCHUNK + chk) * 5) * CH + f;
      t0 += p[0 * CH];
      t1 += p[1 * CH];
      t2 += p[2 * CH];
      t3 += p[3 * CH];
      t4 += p[4 * CH];
    }
    part[0][q][f] = t0;
    part[1][q][f] = t1;
    part[2][q][f] = t2;
    part[3][q][f] = t3;
    part[4][q][f] = t4;
  }
  __syncthreads();

  if (tid < CH) {
    float t0 = part[0][0][tid] + part[0][1][tid] + part[0][2][tid] + part[0][3][tid];
    float t1 = part[1][0][tid] + part[1][1][tid] + part[1][2][tid] + part[1][3][tid];
    float t2 = part[2][0][tid] + part[2][1][tid] + part[2][2][tid] + part[2][3][tid];
    float t3 = part[3][0][tid] + part[3][1][tid] + part[3][2][tid] + part[3][3][tid];
    float t4 = part[4][0][tid] + part[4][1][tid] + part[4][2][tid] + part[4][3][tid];
    float t5 = part[0][3][tid];  // recent = chunks 24..31 == quarter 3
    float t6 = part[1][3][tid];

    const float Lf = (float)LSEQ;
    float mean = t0 / Lf;
    float var = fmaxf(t1 - Lf * mean * mean, 0.f) / (Lf - 1.f);
    float stdE = sqrtf(var) + 1e-8f;
    float m3 = t2 / Lf - 3.f * mean * (t1 / Lf) + 2.f * mean * mean * mean;
    float skew = m3 / (stdE * stdE * stdE);
    const float nd = (float)(LSEQ - 1);
    float dmean = t3 / nd;
    float dvar = fmaxf(t4 - nd * dmean * dmean, 0.f) / (nd - 1.f);
    float dstd = sqrtf(dvar);
    const float nr = (float)NRECENT;
    float rmean = t5 / nr;
    float rvar = fmaxf(t6 - nr * rmean * rmean, 0.f) / (nr - 1.f);
    float rstd = sqrtf(rvar) + 1e-8f;

    stats[0 * CH + tid] = mean;
    stats[1 * CH + tid] = stdE;
    stats[2 * CH + tid] = skew;
    stats[3 * CH + tid] = dstd;
    stats[4 * CH + tid] = rmean;
    stats[5 * CH + tid] = rstd;
  }
  __syncthreads();

  // ---- layer 1: (768) @ (768,128); quarter q covers k in [192q, 192q+192) ----
  {
    const int k0 = 192 * q;
    float a0 = 0, a1 = 0;
#pragma unroll 8
    for (int k = 0; k < 192; k += 2) {
      a0 = fmaf(stats[k0 + k], W1[(size_t)(k0 + k) * 128 + f], a0);
      a1 = fmaf(stats[k0 + k + 1], W1[(size_t)(k0 + k + 1) * 128 + f], a1);
    }
    h1p[q][f] = a0 + a1;
  }
  __syncthreads();
  if (tid < 128) {
    float a = (h1p[0][tid] + h1p[1][tid]) + (h1p[2][tid] + h1p[3][tid]) + b1[tid];
    h1[tid] = 0.5f * a * (1.f + erff(a * 0.70710678118654752f));
  }
  __syncthreads();

  // ---- layer 2: (128) @ (128,32); 16-way split-K ----
  {
    const int f2 = tid & 31, p2 = tid >> 5;  // p2: 0..15, k in [8p2, 8p2+8)
    float a = 0;
#pragma unroll
    for (int k = 8 * p2; k < 8 * p2 + 8; k++)
      a = fmaf(h1[k], W2[k * 32 + f2], a);
    h2p[p2][f2] = a;
  }
  __syncthreads();
  if (tid < 32) {
    float a = b2[tid];
#pragma unroll
    for (int p2 = 0; p2 < 16; p2++) a += h2p[p2][tid];
    h2[tid] = 0.5f * a * (1.f + erff(a * 0.70710678118654752f));
  }
  __syncthreads();

  // ---- layer 3: (32) @ (32,128) + sigmoid; 4-way split-K ----
  {
    float a = 0;
#pragma unroll
    for (int j = 8 * q; j < 8 * q + 8; j++)
      a = fmaf(h2[j], W3[j * 128 + f], a);
    l3p[q][f] = a;
  }
  __syncthreads();
  if (tid < 128) {
    float a = (l3p[0][tid] + l3p[1][tid]) + (l3p[2][tid] + l3p[3][tid]) + b3[tid];
    out[(size_t)b * CH + tid] = 1.f / (1.f + expf(-a));
  }
}

extern "C" void kernel_launch(void* const* d_in, const int* in_sizes, int n_in,
                              void* d_out, int out_size, void* d_ws,
                              size_t ws_size, hipStream_t stream) {
  const float* x = (const float*)d_in[0];
  const float* W1 = (const float*)d_in[1];
  const float* b1 = (const float*)d_in[2];
  const float* W2 = (const float*)d_in[3];
  const float* b2 = (const float*)d_in[4];
  const float* W3 = (const float*)d_in[5];
  const float* b3 = (const float*)d_in[6];
  float* out = (float*)d_out;
  float* ws = (float*)d_ws;

  dim3 g1(NCHUNK, BATCH);
  k_stats_partial<<<g1, 256, 0, stream>>>(x, ws);
  k_stats_mlp<<<BATCH, 512, 0, stream>>>(ws, W1, b1, W2, b2, W3, b3, out);
}